// Round 1
// baseline (4724.055 us; speedup 1.0000x reference)
//
#include <hip/hip_runtime.h>

#define NN 1024
#define BB 8
#define CC 256
#define NBK 32

// ---- output offsets (floats) ----
constexpr size_t OUT_G2P = 8ull * NN * NN;            // 8388608
constexpr size_t OUT_X1  = 16ull * NN * NN;           // 16777216
constexpr size_t OUT_X2  = OUT_X1 + 8ull * NN * CC;   // 18874368
constexpr size_t OUT_L   = OUT_X2 + 8ull * NN * CC;   // 20971520

// ---- workspace offsets (floats) ----
constexpr size_t OFF_ALU    = 0;                        // 16 * 1024 * 1024
constexpr size_t OFF_LOGACC = 16ull * NN * NN;          // 16 (padded 256)
constexpr size_t OFF_PIV    = OFF_LOGACC + 256;         // 512 ints
constexpr size_t OFF_DEG    = OFF_PIV + 512;            // 16384
constexpr size_t OFF_R2N    = OFF_DEG + 16384;          // 2097152
constexpr size_t OFF_LR2    = OFF_R2N + 2097152;        // 2097152
constexpr size_t OFF_LR1    = OFF_LR2 + 2097152;        // 32768
constexpr size_t OFF_X1P    = OFF_LR1 + 32768;          // 32768
constexpr size_t OFF_CS1    = OFF_X1P + 32768;          // 32 (pad 256)
constexpr size_t OFF_CS2    = OFF_CS1 + 256;            // 2048
constexpr size_t OFF_BNP    = OFF_CS2 + 2048;           // 64*512
constexpr size_t OFF_BNS    = OFF_BNP + 32768;          // 768 (pad 1024)
constexpr size_t OFF_WSP    = OFF_BNS + 1024;           // 2048

// ============ pooling: Gp = 0.5*(U.G + (U.G)^T), A = Gp + 1e-3 I ============
__global__ __launch_bounds__(256) void pool_k(const float* __restrict__ G1,
    const float* __restrict__ G2, const float* __restrict__ U1,
    const float* __restrict__ U2, float* __restrict__ out, float* __restrict__ Alu) {
  int mat = blockIdx.z, g = mat >> 3, b = mat & 7;
  const float* G = (g ? G2 : G1) + (size_t)b * NN * NN;
  const float* U = g ? U2 : U1;
  float* Gp = out + (size_t)mat * NN * NN;
  float* A  = Alu + (size_t)mat * NN * NN;
  int ti = blockIdx.y * 64, tj = blockIdx.x * 64;
  int tc = threadIdx.x & 63, tr = threadIdx.x >> 6;
  __shared__ float Wt[64][65];
  #pragma unroll
  for (int s = 0; s < 16; ++s) {
    int r = tr + s * 4;
    size_t idx = (size_t)(tj + r) * NN + (ti + tc);
    Wt[r][tc] = U[idx] * G[idx];
  }
  __syncthreads();
  #pragma unroll
  for (int s = 0; s < 16; ++s) {
    int i = ti + tr + s * 4, j = tj + tc;
    size_t idx = (size_t)i * NN + j;
    float v = 0.5f * (U[idx] * G[idx] + Wt[tc][tr + s * 4]);
    Gp[idx] = v;
    A[idx] = v + ((i == j) ? 1e-3f : 0.0f);
  }
}

// ============ deg[b,i] = sum_j Gp[b,i,j] (one wave per row) ============
__global__ __launch_bounds__(256) void deg_k(const float* __restrict__ out,
                                             float* __restrict__ deg) {
  int wid = threadIdx.x >> 6, lane = threadIdx.x & 63;
  int row = blockIdx.x * 4 + wid;             // 0..16383
  const float* Gp = out + (size_t)row * NN;
  float s = 0.f;
  for (int k = lane; k < NN; k += 64) s += Gp[k];
  #pragma unroll
  for (int o = 32; o; o >>= 1) s += __shfl_down(s, o, 64);
  if (!lane) deg[row] = s;
}

// ============ batchnorm ============
__global__ __launch_bounds__(256) void bn_partial_k(const float* __restrict__ R2,
                                                    float* __restrict__ part) {
  int w = blockIdx.x, c = threadIdx.x;
  float s = 0.f, s2 = 0.f;
  for (int r = w * 128; r < (w + 1) * 128; ++r) {
    float x = R2[(size_t)r * CC + c];
    s += x; s2 += x * x;
  }
  part[w * 512 + c] = s;
  part[w * 512 + 256 + c] = s2;
}

__global__ __launch_bounds__(256) void bn_final_k(const float* __restrict__ part,
    const float* __restrict__ g, const float* __restrict__ bt, float* __restrict__ stats) {
  int c = threadIdx.x;
  float s = 0.f, s2 = 0.f;
  for (int w = 0; w < 64; ++w) { s += part[w * 512 + c]; s2 += part[w * 512 + 256 + c]; }
  float mu = s / 8192.0f, var = s2 / 8192.0f - mu * mu;
  stats[c] = mu;
  stats[256 + c] = rsqrtf(var + 1e-5f) * g[c];
  stats[512 + c] = bt[c];
}

__global__ __launch_bounds__(256) void bn_apply_k(const float* __restrict__ R2,
    const float* __restrict__ stats, float* __restrict__ R2n) {
  int c = threadIdx.x;
  size_t i = (size_t)blockIdx.x * CC + c;
  R2n[i] = (R2[i] - stats[c]) * stats[256 + c] + stats[512 + c];
}

// ============ column sums (ones(N,N) @ V term) ============
__global__ __launch_bounds__(256) void colsum2_k(const float* __restrict__ R2n,
                                                 float* __restrict__ cs2) {
  int b = blockIdx.x, c = threadIdx.x;
  float s = 0.f;
  for (int n = 0; n < NN; ++n) s += R2n[((size_t)b * NN + n) * CC + c];
  cs2[b * CC + c] = s;
}

__global__ __launch_bounds__(64) void colsum1_k(const float* __restrict__ R1,
                                                float* __restrict__ cs1) {
  int t = threadIdx.x;
  if (t >= 32) return;
  int b = t >> 2, c = t & 3;
  float s = 0.f;
  for (int n = 0; n < NN; ++n) s += R1[((size_t)b * NN + n) * 4 + c];
  cs1[b * 4 + c] = s;
}

// ============ LU panel: register-resident, partial pivoting, NB=32 ============
__global__ __launch_bounds__(256) void lu_panel_k(float* __restrict__ Alu, int p,
    float* __restrict__ logacc, int* __restrict__ pivots) {
  const int mat = blockIdx.x;
  float* A = Alu + (size_t)mat * NN * NN;
  const int k0 = p * NBK;
  const int tid = threadIdx.x;
  const int lane = tid & 63, wid = tid >> 6;

  __shared__ float urow[NBK];
  __shared__ float swapA[NBK];
  __shared__ float redv[4];
  __shared__ int   redi[4];
  __shared__ int   s_piv;

  float preg[4][NBK];
  #pragma unroll
  for (int s = 0; s < 4; ++s) {
    const int i = k0 + tid + s * 256;
    if (i < NN) {
      const float* Ar = A + (size_t)i * NN + k0;
      #pragma unroll
      for (int c = 0; c < NBK; ++c) preg[s][c] = Ar[c];
    } else {
      #pragma unroll
      for (int c = 0; c < NBK; ++c) preg[s][c] = 0.0f;
    }
  }

  float lsum = 0.0f;

  for (int j = 0; j < NBK; ++j) {
    // pivot search on current column (preg[.][0]) among rows >= k0+j
    float bv = -1.0f; int br = -1;
    #pragma unroll
    for (int s = 0; s < 4; ++s) {
      const int i = k0 + tid + s * 256;
      if (i < NN && i >= k0 + j) {
        const float v = fabsf(preg[s][0]);
        if (v > bv) { bv = v; br = i; }
      }
    }
    #pragma unroll
    for (int o = 32; o; o >>= 1) {
      const float ov = __shfl_down(bv, o, 64);
      const int   oi = __shfl_down(br, o, 64);
      if (ov > bv) { bv = ov; br = oi; }
    }
    if (lane == 0) { redv[wid] = bv; redi[wid] = br; }
    __syncthreads();                              // B1
    if (tid == 0) {
      float fv = redv[0]; int fi = redi[0];
      #pragma unroll
      for (int wq = 1; wq < 4; ++wq)
        if (redv[wq] > fv) { fv = redv[wq]; fi = redi[wq]; }
      s_piv = fi;
      lsum += logf(fmaxf(fv, 1e-37f));
      pivots[mat * NBK + j] = fi;
    }
    __syncthreads();                              // B2
    const int pr = s_piv;

    // swap streamed L-history (panel cols k0..k0+j-1) between rows k0+j and pr
    if (tid < j && pr != k0 + j) {
      size_t a1 = (size_t)(k0 + j) * NN + k0 + tid;
      size_t a2 = (size_t)pr * NN + k0 + tid;
      float t1 = A[a1], t2 = A[a2];
      A[a1] = t2; A[a2] = t1;
    }

    // register-row swap: ownerA(row k0+j) -> swapA ; ownerB(row pr) -> urow
    {
      const int tb = (pr - k0) & 255;
      const int sb = (pr - k0) >> 8;
      if (tid == j) {
        #pragma unroll
        for (int c = 0; c < NBK; ++c) swapA[c] = preg[0][c];
      }
      if (tid == tb) {
        #pragma unroll
        for (int s = 0; s < 4; ++s) if (s == sb) {
          #pragma unroll
          for (int c = 0; c < NBK; ++c) urow[c] = preg[s][c];
        }
      }
      __syncthreads();                            // B3
      if (tid == tb && pr != k0 + j) {
        #pragma unroll
        for (int s = 0; s < 4; ++s) if (s == sb) {
          #pragma unroll
          for (int c = 0; c < NBK; ++c) preg[s][c] = swapA[c];
        }
      }
    }

    // stream U row (k0+j): cols k0+j .. k0+NBK-1
    const int W = NBK - j;
    if (tid < W) A[(size_t)(k0 + j) * NN + (k0 + j) + tid] = urow[tid];

    // update + shift (L multipliers streamed to global)
    const float pv = urow[0];
    const float pvs = (fabsf(pv) < 1e-37f) ? copysignf(1e-37f, pv) : pv;
    const float ipv = 1.0f / pvs;
    float lmul[4];
    #pragma unroll
    for (int s = 0; s < 4; ++s) {
      const int i = k0 + tid + s * 256;
      const bool act = (i < NN) && (i > k0 + j);
      lmul[s] = act ? preg[s][0] * ipv : 0.0f;
      if (act) A[(size_t)i * NN + (k0 + j)] = lmul[s];
    }
    #pragma unroll
    for (int c = 1; c < NBK; ++c) {
      const float u = urow[c];
      #pragma unroll
      for (int s = 0; s < 4; ++s) preg[s][c - 1] = preg[s][c] - lmul[s] * u;
    }
  }

  if (tid == 0) {
    if (p == 0) logacc[mat] = lsum;
    else        logacc[mat] += lsum;
  }
}

// ============ apply row swaps to trailing cols + TRSM (U12 = L11^-1 A12) ============
__global__ __launch_bounds__(128) void lu_swaptrsm_k(float* __restrict__ Alu, int p,
    const int* __restrict__ pivots) {
  int mat = blockIdx.y;
  float* A = Alu + (size_t)mat * NN * NN;
  int k0 = p * NBK;
  int col = k0 + NBK + blockIdx.x * 128 + threadIdx.x;
  __shared__ float L11[NBK][NBK + 1];
  __shared__ int pv[NBK];
  for (int t = threadIdx.x; t < NBK * NBK; t += 128) {
    int r = t >> 5, c = t & 31;
    L11[r][c] = A[(size_t)(k0 + r) * NN + k0 + c];
  }
  if (threadIdx.x < NBK) pv[threadIdx.x] = pivots[mat * NBK + threadIdx.x];
  __syncthreads();
  if (col >= NN) return;

  #pragma unroll 1
  for (int s = 0; s < NBK; ++s) {
    int r2 = pv[s];
    if (r2 != k0 + s) {
      size_t a1 = (size_t)(k0 + s) * NN + col, a2 = (size_t)r2 * NN + col;
      float t1 = A[a1], t2 = A[a2];
      A[a1] = t2; A[a2] = t1;
    }
  }
  float u[NBK];
  #pragma unroll
  for (int r = 0; r < NBK; ++r) u[r] = A[(size_t)(k0 + r) * NN + col];
  #pragma unroll
  for (int l = 0; l < NBK; ++l) {
    #pragma unroll
    for (int r = 0; r < NBK; ++r)
      if (r > l) u[r] -= L11[r][l] * u[l];
  }
  #pragma unroll
  for (int r = 0; r < NBK; ++r) A[(size_t)(k0 + r) * NN + col] = u[r];
}

// ============ trailing Schur update: A22 -= L21 @ U12 (fp32, 64x64 tile) ============
__global__ __launch_bounds__(256) void lu_gemm_k(float* __restrict__ Alu, int p) {
  int mat = blockIdx.z;
  float* A = Alu + (size_t)mat * NN * NN;
  int k0 = p * NBK;
  int base = k0 + NBK;
  int r0 = base + blockIdx.y * 64, c0 = base + blockIdx.x * 64;
  __shared__ float Ls[64][NBK + 1];
  __shared__ float Us[NBK][64 + 1];
  int tid = threadIdx.x;
  for (int t = tid; t < 64 * NBK; t += 256) {
    int r = t >> 5, c = t & 31;
    Ls[r][c] = (r0 + r < NN) ? A[(size_t)(r0 + r) * NN + k0 + c] : 0.0f;
  }
  for (int t = tid; t < NBK * 64; t += 256) {
    int r = t >> 6, c = t & 63;
    Us[r][c] = (c0 + c < NN) ? A[(size_t)(k0 + r) * NN + c0 + c] : 0.0f;
  }
  __syncthreads();
  int tx = tid & 15, ty = tid >> 4;
  float acc[4][4] = {};
  #pragma unroll
  for (int l = 0; l < NBK; ++l) {
    float a[4], bb[4];
    #pragma unroll
    for (int q = 0; q < 4; ++q) a[q] = Ls[ty * 4 + q][l];
    #pragma unroll
    for (int r = 0; r < 4; ++r) bb[r] = Us[l][tx * 4 + r];
    #pragma unroll
    for (int q = 0; q < 4; ++q)
      #pragma unroll
      for (int r = 0; r < 4; ++r) acc[q][r] += a[q] * bb[r];
  }
  #pragma unroll
  for (int q = 0; q < 4; ++q) {
    int rr = r0 + ty * 4 + q;
    if (rr < NN) {
      #pragma unroll
      for (int r = 0; r < 4; ++r) {
        int cc = c0 + tx * 4 + r;
        if (cc < NN) A[(size_t)rr * NN + cc] -= acc[q][r];
      }
    }
  }
}

// ============ thin GEMV: O = L@V for C=4 (one wave per row) ============
__global__ __launch_bounds__(256) void gemv4_k(const float* __restrict__ Gp,
    const float* __restrict__ V, const float* __restrict__ deg,
    const float* __restrict__ cs, float* __restrict__ O, int mode) {
  int wid = threadIdx.x >> 6, lane = threadIdx.x & 63;
  int row = blockIdx.x * 4 + wid;           // 0..8191
  int b = row >> 10, i = row & 1023;
  const float* Gr = Gp + (size_t)b * NN * NN + (size_t)i * NN;
  const float* Vb = V + (size_t)b * NN * 4;
  float a0 = 0.f, a1 = 0.f, a2 = 0.f, a3 = 0.f;
  for (int k = lane; k < NN; k += 64) {
    float g = Gr[k];
    float4 v = *reinterpret_cast<const float4*>(Vb + (size_t)k * 4);
    a0 += g * v.x; a1 += g * v.y; a2 += g * v.z; a3 += g * v.w;
  }
  #pragma unroll
  for (int o = 32; o; o >>= 1) {
    a0 += __shfl_down(a0, o, 64); a1 += __shfl_down(a1, o, 64);
    a2 += __shfl_down(a2, o, 64); a3 += __shfl_down(a3, o, 64);
  }
  if (lane == 0) {
    float4 v = *reinterpret_cast<const float4*>(Vb + (size_t)i * 4);
    float dg = deg[row];
    float r0 = dg * v.x - a0, r1 = dg * v.y - a1;
    float r2 = dg * v.z - a2, r3 = dg * v.w - a3;
    if (mode) {
      r0 = 2.f * r0 + v.x + cs[b * 4 + 0];
      r1 = 2.f * r1 + v.y + cs[b * 4 + 1];
      r2 = 2.f * r2 + v.z + cs[b * 4 + 2];
      r3 = 2.f * r3 + v.w + cs[b * 4 + 3];
    }
    float4 o4 = {r0, r1, r2, r3};
    *reinterpret_cast<float4*>(O + (size_t)row * 4) = o4;
  }
}

// ============ O = (deg*V - Gp@V) [mode0] or x = 2*(that) + V + cs [mode1] ============
__global__ __launch_bounds__(256) void lgemm_k(const float* __restrict__ Gp,
    const float* __restrict__ V, const float* __restrict__ deg,
    const float* __restrict__ cs, float* __restrict__ O, int mode) {
  int b = blockIdx.z;
  const float* G = Gp + (size_t)b * NN * NN;
  int r0 = blockIdx.y * 64, c0 = blockIdx.x * 64;
  __shared__ float Gs[64][17];
  __shared__ float Vs[16][65];
  float acc[4][4] = {};
  int tid = threadIdx.x, tx = tid & 15, ty = tid >> 4;
  for (int kk = 0; kk < NN; kk += 16) {
    for (int t = tid; t < 64 * 16; t += 256) {
      int r = t >> 4, c = t & 15;
      Gs[r][c] = G[(size_t)(r0 + r) * NN + kk + c];
    }
    for (int t = tid; t < 16 * 64; t += 256) {
      int r = t >> 6, c = t & 63;
      Vs[r][c] = V[((size_t)b * NN + kk + r) * CC + c0 + c];
    }
    __syncthreads();
    #pragma unroll
    for (int l = 0; l < 16; ++l) {
      float a[4], bb[4];
      #pragma unroll
      for (int q = 0; q < 4; ++q) a[q] = Gs[ty * 4 + q][l];
      #pragma unroll
      for (int r = 0; r < 4; ++r) bb[r] = Vs[l][tx * 4 + r];
      #pragma unroll
      for (int q = 0; q < 4; ++q)
        #pragma unroll
        for (int r = 0; r < 4; ++r) acc[q][r] += a[q] * bb[r];
    }
    __syncthreads();
  }
  #pragma unroll
  for (int q = 0; q < 4; ++q) {
    int i = r0 + ty * 4 + q;
    float dg = deg[b * NN + i];
    #pragma unroll
    for (int r = 0; r < 4; ++r) {
      int c = c0 + tx * 4 + r;
      float v = V[((size_t)b * NN + i) * CC + c];
      float val = dg * v - acc[q][r];
      if (mode) val = 2.f * val + v + cs[b * CC + c];
      O[((size_t)b * NN + i) * CC + c] = val;
    }
  }
}

// ============ conv1d: [B,N,4] -> [B,N,256], K=5, pad 2 ============
__global__ __launch_bounds__(256) void conv_k(const float* __restrict__ xp,
    const float* __restrict__ w, const float* __restrict__ bias,
    float* __restrict__ x1out) {
  int bn = blockIdx.x;
  int b = bn >> 10, n = bn & 1023;
  int co = threadIdx.x;
  __shared__ float xs[5][4];
  if (threadIdx.x < 20) {
    int k = threadIdx.x >> 2, ci = threadIdx.x & 3;
    int n2 = n + k - 2;
    xs[k][ci] = (n2 >= 0 && n2 < NN) ? xp[((size_t)b * NN + n2) * 4 + ci] : 0.0f;
  }
  __syncthreads();
  const float* wp = w + co * 20;
  float acc = bias[co];
  #pragma unroll
  for (int ci = 0; ci < 4; ++ci)
    #pragma unroll
    for (int k = 0; k < 5; ++k) acc += wp[ci * 5 + k] * xs[k][ci];
  x1out[((size_t)b * NN + n) * CC + co] = acc;
}

// ============ Wasserstein: bitonic sort 1024 per (b,c), sum |s1-s2| ============
__global__ __launch_bounds__(256) void wass_k(const float* __restrict__ x1,
    const float* __restrict__ x2, float* __restrict__ part) {
  int bc = blockIdx.x;
  int b = bc >> 8, c = bc & 255;
  __shared__ float s1[1024];
  __shared__ float s2[1024];
  __shared__ float red[256];
  int t = threadIdx.x;
  for (int q = 0; q < 4; ++q) {
    int n = t + q * 256;
    s1[n] = x1[((size_t)b * NN + n) * CC + c];
    s2[n] = x2[((size_t)b * NN + n) * CC + c];
  }
  __syncthreads();
  for (int k = 2; k <= 1024; k <<= 1) {
    for (int j = k >> 1; j > 0; j >>= 1) {
      #pragma unroll
      for (int q = 0; q < 2; ++q) {
        int idx = t + q * 256;
        int i = ((idx & ~(j - 1)) << 1) | (idx & (j - 1));
        int l = i | j;
        bool up = ((i & k) == 0);
        float a = s1[i], bv = s1[l];
        if ((a > bv) == up) { s1[i] = bv; s1[l] = a; }
        a = s2[i]; bv = s2[l];
        if ((a > bv) == up) { s2[i] = bv; s2[l] = a; }
      }
      __syncthreads();
    }
  }
  float s = 0.f;
  for (int q = 0; q < 4; ++q) {
    int n = t + q * 256;
    s += fabsf(s1[n] - s2[n]);
  }
  red[t] = s;
  __syncthreads();
  for (int o = 128; o; o >>= 1) {
    if (t < o) red[t] += red[t + o];
    __syncthreads();
  }
  if (!t) part[bc] = red[0];
}

// ============ finalize losses ============
__global__ __launch_bounds__(256) void finalize_k(const float* __restrict__ logacc,
    const float* __restrict__ part, float* __restrict__ out) {
  int t = threadIdx.x;
  __shared__ double red[256];
  double s = 0.0;
  for (int i = t; i < 2048; i += 256) s += (double)part[i];
  red[t] = s;
  __syncthreads();
  for (int o = 128; o; o >>= 1) {
    if (t < o) red[t] += red[t + o];
    __syncthreads();
  }
  if (!t) {
    double l1 = 0.0, l2 = 0.0;
    for (int i = 0; i < 8; ++i) { l1 += (double)logacc[i]; l2 += (double)logacc[8 + i]; }
    out[OUT_L + 0] = (float)(-l1 / 8.0);
    out[OUT_L + 1] = (float)(-l2 / 8.0);
    out[OUT_L + 2] = (float)(red[0] / 2097152.0);
  }
}

extern "C" void kernel_launch(void* const* d_in, const int* in_sizes, int n_in,
                              void* d_out, int out_size, void* d_ws, size_t ws_size,
                              hipStream_t stream) {
  (void)in_sizes; (void)n_in; (void)out_size; (void)ws_size;
  const float* G1 = (const float*)d_in[0];
  const float* G2 = (const float*)d_in[1];
  const float* R1 = (const float*)d_in[2];
  const float* R2 = (const float*)d_in[3];
  const float* U1 = (const float*)d_in[7];
  const float* U2 = (const float*)d_in[8];
  const float* CW = (const float*)d_in[9];
  const float* CB = (const float*)d_in[10];
  const float* BG = (const float*)d_in[11];
  const float* BBt = (const float*)d_in[12];
  float* out = (float*)d_out;
  float* ws = (float*)d_ws;

  float* Alu    = ws + OFF_ALU;
  float* logacc = ws + OFF_LOGACC;
  int*   piv    = (int*)(ws + OFF_PIV);
  float* deg    = ws + OFF_DEG;
  float* R2n    = ws + OFF_R2N;
  float* LR2    = ws + OFF_LR2;
  float* LR1    = ws + OFF_LR1;
  float* X1P    = ws + OFF_X1P;
  float* CS1    = ws + OFF_CS1;
  float* CS2    = ws + OFF_CS2;
  float* BNP    = ws + OFF_BNP;
  float* BNS    = ws + OFF_BNS;
  float* WSP    = ws + OFF_WSP;

  pool_k<<<dim3(16, 16, 16), 256, 0, stream>>>(G1, G2, U1, U2, out, Alu);
  deg_k<<<4096, 256, 0, stream>>>(out, deg);

  bn_partial_k<<<64, 256, 0, stream>>>(R2, BNP);
  bn_final_k<<<1, 256, 0, stream>>>(BNP, BG, BBt, BNS);
  bn_apply_k<<<8192, 256, 0, stream>>>(R2, BNS, R2n);
  colsum2_k<<<8, 256, 0, stream>>>(R2n, CS2);
  colsum1_k<<<1, 64, 0, stream>>>(R1, CS1);

  // x1 path: LR1 = L1@R1 ; x1pre = 2*L1@LR1 + LR1 + colsum(R1) ; conv
  gemv4_k<<<2048, 256, 0, stream>>>(out, R1, deg, CS1, LR1, 0);
  gemv4_k<<<2048, 256, 0, stream>>>(out, LR1, deg, CS1, X1P, 1);
  conv_k<<<8192, 256, 0, stream>>>(X1P, CW, CB, out + OUT_X1);

  // x2 path: LR2 = L2@R2n ; x2 = 2*L2@LR2 + LR2 + colsum(R2n)
  lgemm_k<<<dim3(4, 16, 8), 256, 0, stream>>>(out + OUT_G2P, R2n, deg + 8192, CS2, LR2, 0);
  lgemm_k<<<dim3(4, 16, 8), 256, 0, stream>>>(out + OUT_G2P, LR2, deg + 8192, CS2, out + OUT_X2, 1);

  // blocked LU with partial pivoting on A = Gp + 1e-3 I (16 matrices)
  for (int p = 0; p < NN / NBK; ++p) {
    lu_panel_k<<<16, 256, 0, stream>>>(Alu, p, logacc, piv);
    int rem = NN - (p + 1) * NBK;
    if (rem > 0) {
      int bx = (rem + 127) / 128;
      lu_swaptrsm_k<<<dim3(bx, 16), 128, 0, stream>>>(Alu, p, piv);
      int mt = (rem + 63) / 64;
      lu_gemm_k<<<dim3(mt, mt, 16), 256, 0, stream>>>(Alu, p);
    }
  }

  wass_k<<<2048, 256, 0, stream>>>(out + OUT_X1, out + OUT_X2, WSP);
  finalize_k<<<1, 256, 0, stream>>>(logacc, WSP, out);
}